// Round 10
// baseline (634.416 us; speedup 1.0000x reference)
//
#include <hip/hip_runtime.h>

#define N_NODES 100000
#define N_PAD   100032            // 1563 * 64
#define R_REL   8
#define D_DIM   64
#define E_EDGES 3200000
#define NSEG    (N_NODES * R_REL)             // 800000
#define NB      391                            // dst buckets (dst>>8)
#define SEG_PER_BKT 2048                       // 256 nodes * 8 rel
#define BKT_CAP 9000                           // mean 8192 + ~9 sigma
#define P1_BLOCKS 512
#define P1_CHUNK  (E_EDGES / P1_BLOCKS)        // 6250

typedef __attribute__((ext_vector_type(8))) short short8;   // 8 bf16 (4 VGPRs)
typedef __attribute__((ext_vector_type(4))) float f32x4;

__device__ __forceinline__ unsigned short f2bf(float f) {   // RNE float->bf16
    unsigned u = __float_as_uint(f);
    u += 0x7fffu + ((u >> 16) & 1u);
    return (unsigned short)(u >> 16);
}

__device__ __forceinline__ int epack(int s, int d, int r) {
    return (s << 11) | ((d & 255) << 3) | r;
}

// --- emb fp32 -> bf16 ------------------------------------------------------
__global__ void __launch_bounds__(256)
cvt_kernel(const float* __restrict__ in, unsigned short* __restrict__ outb) {
    size_t base = ((size_t)blockIdx.x * 256 + threadIdx.x) * 8;
    float4 v0 = *(const float4*)(in + base);
    float4 v1 = *(const float4*)(in + base + 4);
    uint4 o;
    o.x = f2bf(v0.x) | ((unsigned)f2bf(v0.y) << 16);
    o.y = f2bf(v0.z) | ((unsigned)f2bf(v0.w) << 16);
    o.z = f2bf(v1.x) | ((unsigned)f2bf(v1.y) << 16);
    o.w = f2bf(v1.z) | ((unsigned)f2bf(v1.w) << 16);
    *(uint4*)(outb + base) = o;
}

__global__ void init_cursor_kernel(int* __restrict__ bkt_cursor) {
    int t = blockIdx.x * 256 + threadIdx.x;
    if (t <= NB) bkt_cursor[t] = t * BKT_CAP;
}

// --- P1: partition edges into fixed-capacity dst-buckets -------------------
// 4-edge batches: 4 independent load->LDS-atomic->store chains in flight.
__global__ void __launch_bounds__(256)
p1_scatter_kernel(const int* __restrict__ src, const int* __restrict__ dst,
                  const int* __restrict__ et, int* __restrict__ bkt_cursor,
                  int* __restrict__ packed) {
    __shared__ int hist[NB];
    __shared__ int cur[NB];
    int t = threadIdx.x;
    for (int i = t; i < NB; i += 256) hist[i] = 0;
    __syncthreads();
    int base = blockIdx.x * P1_CHUNK;
    {
        int i = t;
        for (; i + 768 < P1_CHUNK; i += 1024) {
            int e0 = base + i, e1 = e0 + 256, e2 = e0 + 512, e3 = e0 + 768;
            atomicAdd(&hist[dst[e0] >> 8], 1);
            atomicAdd(&hist[dst[e1] >> 8], 1);
            atomicAdd(&hist[dst[e2] >> 8], 1);
            atomicAdd(&hist[dst[e3] >> 8], 1);
        }
        for (; i < P1_CHUNK; i += 256)
            atomicAdd(&hist[dst[base + i] >> 8], 1);
    }
    __syncthreads();
    for (int i = t; i < NB; i += 256) {
        int c = hist[i];
        cur[i] = c ? atomicAdd(&bkt_cursor[i], c) : 0;    // reserve block's run
    }
    __syncthreads();
    {
        int i = t;
        for (; i + 768 < P1_CHUNK; i += 1024) {
            int e0 = base + i, e1 = e0 + 256, e2 = e0 + 512, e3 = e0 + 768;
            int d0 = dst[e0], d1 = dst[e1], d2 = dst[e2], d3 = dst[e3];
            int r0 = et[e0],  r1 = et[e1],  r2 = et[e2],  r3 = et[e3];
            int s0 = src[e0], s1 = src[e1], s2 = src[e2], s3 = src[e3];
            int p0 = atomicAdd(&cur[d0 >> 8], 1);
            int p1 = atomicAdd(&cur[d1 >> 8], 1);
            int p2 = atomicAdd(&cur[d2 >> 8], 1);
            int p3 = atomicAdd(&cur[d3 >> 8], 1);
            packed[p0] = epack(s0, d0, r0);
            packed[p1] = epack(s1, d1, r1);
            packed[p2] = epack(s2, d2, r2);
            packed[p3] = epack(s3, d3, r3);
        }
        for (; i < P1_CHUNK; i += 256) {
            int e = base + i;
            int d = dst[e];
            int pos = atomicAdd(&cur[d >> 8], 1);
            packed[pos] = epack(src[e], d, et[e]);
        }
    }
}

// --- P2: per-bucket counting sort in LDS -> sorted esrc + starts/ends ------
__global__ void __launch_bounds__(256)
p2_sort_kernel(const int* __restrict__ packed, const int* __restrict__ bkt_cursor,
               int* __restrict__ starts, int* __restrict__ ends, int* __restrict__ esrc) {
    __shared__ int shist[SEG_PER_BKT];
    __shared__ int scur[SEG_PER_BKT];
    __shared__ int stmp[256];
    int b = blockIdx.x;
    int t = threadIdx.x;
    int ebase = b * BKT_CAP;
    int eend  = bkt_cursor[b];                            // == ebase + bucket count
    int segbase = b * SEG_PER_BKT;
    int nseg = NSEG - segbase; if (nseg > SEG_PER_BKT) nseg = SEG_PER_BKT;
#pragma unroll
    for (int i = 0; i < 8; ++i) shist[t + i * 256] = 0;
    __syncthreads();
    for (int e = ebase + t; e < eend; e += 256)
        atomicAdd(&shist[packed[e] & 2047], 1);
    __syncthreads();
    int loc[8], s = 0;
    int b8 = t * 8;
#pragma unroll
    for (int i = 0; i < 8; ++i) { loc[i] = shist[b8 + i]; s += loc[i]; }
    stmp[t] = s;
    __syncthreads();
    for (int off = 1; off < 256; off <<= 1) {
        int x = (t >= off) ? stmp[t - off] : 0;
        __syncthreads();
        stmp[t] += x;
        __syncthreads();
    }
    int run = (t == 0) ? 0 : stmp[t - 1];
#pragma unroll
    for (int i = 0; i < 8; ++i) {
        shist[b8 + i] = run; scur[b8 + i] = run;
        run += loc[i];
    }
    __syncthreads();
    for (int i = t; i < nseg; i += 256)
        starts[segbase + i] = ebase + shist[i];
    for (int e = ebase + t; e < eend; e += 256) {
        int p = packed[e];
        int r = atomicAdd(&scur[p & 2047], 1);
        esrc[ebase + r] = p >> 11;
    }
    __syncthreads();
    for (int i = t; i < nseg; i += 256)
        ends[segbase + i] = ebase + scur[i];
}

// --- W prep: transpose W[r][k][d] -> wbuf[r][d][k] in bf16 (r=8 is root) ----
__global__ void wprep_kernel(const float* __restrict__ W, const float* __restrict__ root,
                             unsigned short* __restrict__ wbuf) {
    int r = blockIdx.x;
    const float* src = (r < 8) ? (W + (size_t)r * 4096) : root;
    __shared__ float t[64][65];
    int a = threadIdx.x >> 2, c = threadIdx.x & 3;
#pragma unroll
    for (int i = 0; i < 4; ++i) {
        float4 v = *(const float4*)(src + a * 64 + c * 16 + i * 4);
        t[a][c * 16 + i * 4 + 0] = v.x;
        t[a][c * 16 + i * 4 + 1] = v.y;
        t[a][c * 16 + i * 4 + 2] = v.z;
        t[a][c * 16 + i * 4 + 3] = v.w;
    }
    __syncthreads();
    unsigned short* outrow = wbuf + (size_t)r * 4096 + a * 64;
#pragma unroll
    for (int i = 0; i < 4; ++i) {
        int k0 = c * 16 + i * 4;
        ushort4 o;
        o.x = f2bf(t[k0 + 0][a]); o.y = f2bf(t[k0 + 1][a]);
        o.z = f2bf(t[k0 + 2][a]); o.w = f2bf(t[k0 + 3][a]);
        *(ushort4*)(outrow + k0) = o;
    }
}

// --- fused layer, BARRIER-FREE: per-wave private A-tile (16 nodes) ---------
// Wave w owns nodes n0..n0+15. Per phase p: 4 groups of 16 lanes gather+mean
// 4 nodes each straight into the wave's LDS tile (lockstep wave => no
// __syncthreads, only an LDS fence), then MFMA with B direct from L1-hot wbuf.
__global__ void __launch_bounds__(256)
fused_kernel(const unsigned short* __restrict__ hb, const int* __restrict__ esrc,
             const int* __restrict__ starts, const int* __restrict__ ends,
             const unsigned short* __restrict__ wbuf, const float* __restrict__ bias,
             void* __restrict__ out, int mode) {
    __shared__ unsigned short As[4][16 * 72];              // per-wave tile
    int tid = threadIdx.x;
    int w = tid >> 6, lane = tid & 63;
    int ml = lane & 15, kg = lane >> 4;
    int n0 = blockIdx.x * 64 + w * 16;                     // wave's node base
    unsigned short* A = As[w];

    f32x4 acc[4] = {{0,0,0,0},{0,0,0,0},{0,0,0,0},{0,0,0,0}};

    for (int p = 0; p < 9; ++p) {
        if (p < 8) {
            // group kg gathers nodes kg*4+jj; lane ml = dim quad
            for (int jj = 0; jj < 4; ++jj) {
                int nl = kg * 4 + jj;
                int node = n0 + nl;
                float a0 = 0.f, a1 = 0.f, a2 = 0.f, a3 = 0.f;
                int cnt = 0;
                if (node < N_NODES) {
                    int seg = node * R_REL + p;
                    int beg = starts[seg], end = ends[seg];
                    cnt = end - beg;
                    if (beg < end) {
                        int s = esrc[beg];
                        uint2 v = *(const uint2*)(hb + (size_t)s * D_DIM + ml * 4);
                        for (int e = beg + 1; e < end; ++e) {
                            int s2 = esrc[e];
                            uint2 v2 = *(const uint2*)(hb + (size_t)s2 * D_DIM + ml * 4);
                            a0 += __uint_as_float(v.x << 16);
                            a1 += __uint_as_float(v.x & 0xffff0000u);
                            a2 += __uint_as_float(v.y << 16);
                            a3 += __uint_as_float(v.y & 0xffff0000u);
                            v = v2;
                        }
                        a0 += __uint_as_float(v.x << 16);
                        a1 += __uint_as_float(v.x & 0xffff0000u);
                        a2 += __uint_as_float(v.y << 16);
                        a3 += __uint_as_float(v.y & 0xffff0000u);
                    }
                }
                float inv = 1.0f / fmaxf((float)cnt, 1.0f);
                ushort4 o;
                o.x = f2bf(a0 * inv); o.y = f2bf(a1 * inv);
                o.z = f2bf(a2 * inv); o.w = f2bf(a3 * inv);
                *(ushort4*)(A + nl * 72 + ml * 4) = o;
            }
        } else {
            // root phase: copy wave's own 16 h rows (bf16)
            int row = lane >> 2, c = lane & 3;
            int rr = n0 + row; if (rr >= N_NODES) rr = N_NODES - 1;
            const unsigned short* hp = hb + (size_t)rr * D_DIM + c * 16;
            uint4 v0 = *(const uint4*)(hp);
            uint4 v1 = *(const uint4*)(hp + 8);
            *(uint4*)(A + row * 72 + c * 16)     = v0;
            *(uint4*)(A + row * 72 + c * 16 + 8) = v1;
        }
        __threadfence_block();                             // LDS writes -> reads (in-wave)
        short8 A0 = *(const short8*)(A + ml * 72 + kg * 8);        // k 0..31
        short8 A1 = *(const short8*)(A + ml * 72 + 32 + kg * 8);   // k 32..63
        __threadfence_block();                             // reads before next overwrite
        const unsigned short* wp = wbuf + (size_t)p * 4096;
#pragma unroll
        for (int dt = 0; dt < 4; ++dt) {
            const unsigned short* bp = wp + (dt * 16 + ml) * 64 + kg * 8;
            short8 B0 = *(const short8*)(bp);              // L1-hot
            short8 B1 = *(const short8*)(bp + 32);
            acc[dt] = __builtin_amdgcn_mfma_f32_16x16x32_bf16(A0, B0, acc[dt], 0, 0, 0);
            acc[dt] = __builtin_amdgcn_mfma_f32_16x16x32_bf16(A1, B1, acc[dt], 0, 0, 0);
        }
    }
    // epilogue: C layout col = ml (d), row = kg*4 + reg (node within wave tile)
#pragma unroll
    for (int dt = 0; dt < 4; ++dt) {
        float bv = bias[dt * 16 + ml];
#pragma unroll
        for (int rg = 0; rg < 4; ++rg) {
            int node = n0 + kg * 4 + rg;
            if (node < N_NODES) {
                float v = acc[dt][rg] + bv;
                if (mode) {
                    v = fmaxf(v, 0.f);
                    ((unsigned short*)out)[(size_t)node * D_DIM + dt * 16 + ml] = f2bf(v);
                } else {
                    ((float*)out)[(size_t)node * D_DIM + dt * 16 + ml] = v;
                }
            }
        }
    }
}

// --- launch ---------------------------------------------------------------

extern "C" void kernel_launch(void* const* d_in, const int* in_sizes, int n_in,
                              void* d_out, int out_size, void* d_ws, size_t ws_size,
                              hipStream_t stream) {
    const int*   ei    = (const int*)d_in[1];
    const int*   src   = ei;
    const int*   dst   = ei + E_EDGES;
    const int*   et    = (const int*)d_in[2];
    const float* emb   = (const float*)d_in[3];   // x = arange(N): identity remap
    const float* W1    = (const float*)d_in[4];
    const float* root1 = (const float*)d_in[5];
    const float* b1    = (const float*)d_in[6];
    const float* W2    = (const float*)d_in[7];
    const float* root2 = (const float*)d_in[8];
    const float* b2    = (const float*)d_in[9];
    float*       out   = (float*)d_out;

    // workspace layout (bf16 blocks first: all 16B-aligned)
    unsigned short* embb   = (unsigned short*)d_ws;                      // [N*64] bf16
    unsigned short* h1b    = embb + (size_t)N_NODES * D_DIM;             // [N_PAD*64] bf16
    unsigned short* wbuf1  = h1b + (size_t)N_PAD * D_DIM;                // [9*4096] bf16
    unsigned short* wbuf2  = wbuf1 + 9 * 4096;
    int*            starts = (int*)(wbuf2 + 9 * 4096);                   // [NSEG]
    int*            ends   = starts + NSEG;                              // [NSEG]
    int*            packed = ends + NSEG;                                // [NB*CAP]
    int*            esrc   = packed + (size_t)NB * BKT_CAP;              // [NB*CAP]
    int*            bkt_cursor = esrc + (size_t)NB * BKT_CAP;            // [NB+1]

    // ---- CSR build: fixed-capacity buckets, no global hist/scan ----
    init_cursor_kernel<<<2, 256, 0, stream>>>(bkt_cursor);
    p1_scatter_kernel <<<P1_BLOCKS, 256, 0, stream>>>(src, dst, et, bkt_cursor, packed);
    p2_sort_kernel    <<<NB, 256, 0, stream>>>(packed, bkt_cursor, starts, ends, esrc);

    // ---- prep: weights (bf16 transposed) + emb bf16 copy ----
    wprep_kernel<<<9, 256, 0, stream>>>(W1, root1, wbuf1);
    wprep_kernel<<<9, 256, 0, stream>>>(W2, root2, wbuf2);
    cvt_kernel<<<(N_NODES * D_DIM) / 2048, 256, 0, stream>>>(emb, embb);

    const int blocks = N_PAD / 64;               // 1563

    // ---- layer 1: emb -> h1b (ReLU, bf16) ----
    fused_kernel<<<blocks, 256, 0, stream>>>(embb, esrc, starts, ends, wbuf1, b1, h1b, 1);
    // ---- layer 2: h1b -> out (fp32) ----
    fused_kernel<<<blocks, 256, 0, stream>>>(h1b, esrc, starts, ends, wbuf2, b2, out, 0);
}